// Round 11
// baseline (390.811 us; speedup 1.0000x reference)
//
#include <hip/hip_runtime.h>
#include <hip/hip_bf16.h>

typedef __bf16 bf8 __attribute__((ext_vector_type(8)));
typedef __bf16 bfx4 __attribute__((ext_vector_type(4)));
typedef float f4 __attribute__((ext_vector_type(4)));

#define NTOK 9216
#define CDIM 256
#define LOG2E 1.44269504f
#define PSHIFT 32.0f

// ---- MFMA fragment helpers (16x16x32 bf16) --------------------------------
// A[m][k]: lane m=l&15, k=(l>>4)*8+j ; Bt[n][k] same ; D: row=(l>>4)*4+reg,
// col=l&15
__device__ inline bf8 ldfrag(const __bf16* p, int ld) {
  int l = threadIdx.x & 63;
  return *reinterpret_cast<const bf8*>(p + (l & 15) * ld + ((l >> 4) << 3));
}
__device__ inline f4 mfma16(bf8 a, bf8 b, f4 c) {
  return __builtin_amdgcn_mfma_f32_16x16x32_bf16(a, b, c, 0, 0, 0);
}
// async global->LDS, 16B per lane; LDS dest = base + lane*16 (wave-uniform base)
__device__ inline void gl2lds(const __bf16* g, __bf16* l) {
  __builtin_amdgcn_global_load_lds(
      (const __attribute__((address_space(1))) void*)g,
      (__attribute__((address_space(3))) void*)l, 16, 0, 0);
}

// ---- generic GEMM: C[M][N] = A[M][K](lda) x Bt[N][K](ldb)^T ----------------
// 128x128 tile, BK=32, 4 waves in 2x2. 2-buffer counted-vmcnt pipeline
// (sgemm-verified): issue step s+2 into buf[s&1] after barrier-2.
// EPI: 1 = store bf16 row-major
//      4 = fused final: out[z][row][col] = acc + aux1[row]*aux0[z*NTOK+col],
//          z in [blockIdx.z*2, blockIdx.z*2+2)
template <int EPI>
__global__ __launch_bounds__(256) void gemm128(const __bf16* __restrict__ A, int lda,
                                               const __bf16* __restrict__ Bt, int ldb,
                                               void* __restrict__ Cv, int ldc, int K,
                                               const float* __restrict__ aux0,
                                               const float* __restrict__ aux1) {
  __shared__ __bf16 As[2][128 * 32];
  __shared__ __bf16 Bs[2][128 * 32];
  const int tid = threadIdx.x;
  const int w = tid >> 6, lane = tid & 63;
  const int lc = lane & 15, quad = lane >> 4;
  const int m0 = blockIdx.x * 128, n0 = blockIdx.y * 128;
  const int wm = (w & 1) << 6, wn = (w >> 1) << 6;
  // staging: wave w fills LDS chunks 2w, 2w+1 of A and B (16 rows x 32k each)
  const int r0 = (w * 2) * 16 + (lane >> 2);
  const int cg = (lane & 3) * 8;
  const __bf16* gA0 = A + (size_t)(m0 + r0) * lda + cg;
  const __bf16* gA1 = A + (size_t)(m0 + r0 + 16) * lda + cg;
  const __bf16* gB0 = Bt + (size_t)(n0 + r0) * ldb + cg;
  const __bf16* gB1 = Bt + (size_t)(n0 + r0 + 16) * ldb + cg;
  const int la = w * 1024;

  // prologue: issue K-steps 0,1 into bufs 0,1
  for (int p = 0; p < 2; p++) {
    gl2lds(gA0 + p * 32, &As[p][la]);
    gl2lds(gA1 + p * 32, &As[p][la + 512]);
    gl2lds(gB0 + p * 32, &Bs[p][la]);
    gl2lds(gB1 + p * 32, &Bs[p][la + 512]);
  }

  f4 acc[4][4] = {};
  const int nst = K / 32;
  for (int s = 0; s < nst; s++) {
    const int cur = s & 1;
    asm volatile("s_waitcnt vmcnt(4)" ::: "memory");
    __builtin_amdgcn_sched_barrier(0);
    __builtin_amdgcn_s_barrier();  // barrier 1: tile s complete in buf[cur]
    __builtin_amdgcn_sched_barrier(0);
    bf8 af[4], bfr[4];
    for (int i = 0; i < 4; i++) af[i] = ldfrag(&As[cur][(wm + 16 * i) * 32], 32);
    for (int j = 0; j < 4; j++) bfr[j] = ldfrag(&Bs[cur][(wn + 16 * j) * 32], 32);
    __builtin_amdgcn_s_setprio(1);
    for (int i = 0; i < 4; i++)
      for (int j = 0; j < 4; j++) acc[i][j] = mfma16(af[i], bfr[j], acc[i][j]);
    __builtin_amdgcn_s_setprio(0);
    __builtin_amdgcn_sched_barrier(0);
    __builtin_amdgcn_s_barrier();  // barrier 2: all reads of buf[cur] done
    __builtin_amdgcn_sched_barrier(0);
    int sp = (s + 2 < nst) ? s + 2 : nst - 1;  // clamped tail re-issues data
    gl2lds(gA0 + sp * 32, &As[cur][la]);
    gl2lds(gA1 + sp * 32, &As[cur][la + 512]);
    gl2lds(gB0 + sp * 32, &Bs[cur][la]);
    gl2lds(gB1 + sp * 32, &Bs[cur][la + 512]);
  }
  asm volatile("s_waitcnt vmcnt(0)" ::: "memory");

  if (EPI == 4) {
    float* outp = (float*)Cv;
    const int z0 = blockIdx.z * 2;
    for (int i = 0; i < 4; i++)
      for (int r = 0; r < 4; r++) {
        int o = m0 + wm + 16 * i + quad * 4 + r;
        float wo = aux1[o];
        for (int j = 0; j < 4; j++) {
          int n = n0 + wn + 16 * j + lc;
          float b = acc[i][j][r];
          for (int z = z0; z < z0 + 2; z++)
            outp[((size_t)z * 256 + o) * NTOK + n] =
                b + wo * aux0[(size_t)z * NTOK + n];
        }
      }
  } else {
    for (int i = 0; i < 4; i++)
      for (int j = 0; j < 4; j++)
        for (int r = 0; r < 4; r++) {
          size_t idx = (size_t)(m0 + wm + 16 * i + quad * 4 + r) * ldc +
                       (n0 + wn + 16 * j + lc);
          ((__bf16*)Cv)[idx] = (__bf16)acc[i][j][r];
        }
  }
}

// ---- S-GEMM (swapped): D[kt][q] = Kt x Qt^T, P = bf16(exp2(D-PSHIFT)) ------
// 2-buffer double-buffered pipeline, counted vmcnt(4), 2 barriers/step; issue
// of step s+2 strictly after barrier-2 (all readers of buf[s&1] done).
// Epilogue: 4 consecutive kt per lane pack into one aligned b64 global store
// in the step-tiled chunk-swizzled P layout; 16-lane column-sum -> Pd.
__global__ __launch_bounds__(256) void sgemm_kernel(const __bf16* __restrict__ Kt,
                                                    const __bf16* __restrict__ Qt,
                                                    __bf16* __restrict__ Pp,
                                                    float* __restrict__ Pd) {
  __shared__ __bf16 As[2][128 * 32];
  __shared__ __bf16 Bs[2][128 * 32];
  const int tid = threadIdx.x;
  const int w = tid >> 6, lane = tid & 63;
  const int lc = lane & 15, quad = lane >> 4;
  const int m0 = blockIdx.x * 128;  // kt tile
  const int n0 = blockIdx.y * 128;  // q tile
  const int wm = (w & 1) << 6, wn = (w >> 1) << 6;
  // staging: wave w stages rows [32w, 32w+32) of A and B; 2 gl2lds each
  const int r0 = w * 32 + (lane >> 2);
  const int cg = (lane & 3) * 8;
  const __bf16* gA0 = Kt + (size_t)(m0 + r0) * 512 + cg;
  const __bf16* gA1 = Kt + (size_t)(m0 + r0 + 16) * 512 + cg;
  const __bf16* gB0 = Qt + (size_t)(n0 + r0) * 512 + cg;
  const __bf16* gB1 = Qt + (size_t)(n0 + r0 + 16) * 512 + cg;
  const int la = w * 1024;

  // prologue: issue K-steps 0,1 into bufs 0,1
  for (int p = 0; p < 2; p++) {
    gl2lds(gA0 + p * 32, &As[p][la]);
    gl2lds(gA1 + p * 32, &As[p][la + 512]);
    gl2lds(gB0 + p * 32, &Bs[p][la]);
    gl2lds(gB1 + p * 32, &Bs[p][la + 512]);
  }

  f4 acc[4][4] = {};
  for (int s = 0; s < 8; s++) {
    const int cur = s & 1;
    asm volatile("s_waitcnt vmcnt(4)" ::: "memory");
    __builtin_amdgcn_sched_barrier(0);
    __builtin_amdgcn_s_barrier();  // barrier 1: tile s complete in buf[cur]
    __builtin_amdgcn_sched_barrier(0);
    bf8 af[4], bfr[4];
    for (int i = 0; i < 4; i++) af[i] = ldfrag(&As[cur][(wm + 16 * i) * 32], 32);
    for (int j = 0; j < 4; j++) bfr[j] = ldfrag(&Bs[cur][(wn + 16 * j) * 32], 32);
    __builtin_amdgcn_s_setprio(1);
    for (int i = 0; i < 4; i++)
      for (int j = 0; j < 4; j++) acc[i][j] = mfma16(af[i], bfr[j], acc[i][j]);
    __builtin_amdgcn_s_setprio(0);
    __builtin_amdgcn_sched_barrier(0);
    __builtin_amdgcn_s_barrier();  // barrier 2: all reads of buf[cur] done
    __builtin_amdgcn_sched_barrier(0);
    int sp = (s + 2 < 8) ? s + 2 : 7;  // clamped tail re-issues same data
    gl2lds(gA0 + sp * 32, &As[cur][la]);
    gl2lds(gA1 + sp * 32, &As[cur][la + 512]);
    gl2lds(gB0 + sp * 32, &Bs[cur][la]);
    gl2lds(gB1 + sp * 32, &Bs[cur][la + 512]);
  }

  // epilogue: kt = m0+wm+16i+quad*4+r, q = n0+wn+16j+lc
  float dsum[4][4];
  for (int i = 0; i < 4; i++)
    for (int r = 0; r < 4; r++) dsum[i][r] = 0.f;
  for (int j = 0; j < 4; j++) {
    int q = n0 + wn + 16 * j + lc;
    for (int i = 0; i < 4; i++) {
      int ktb = m0 + wm + 16 * i;  // + quad*4 stays within 32-group
      int c2 = ((i & 1) << 1) | (quad >> 1);
      bfx4 pk;
      for (int r = 0; r < 4; r++) {
        float e = exp2f(acc[i][j][r] - PSHIFT);
        dsum[i][r] += e;
        pk[r] = (__bf16)e;
      }
      __bf16* dst = Pp + ((size_t)(ktb >> 5) * NTOK + q) * 32 +
                    ((c2 ^ (lc & 3)) << 3) + ((quad & 1) << 2);
      *reinterpret_cast<bfx4*>(dst) = pk;
    }
  }
  for (int i = 0; i < 4; i++)
    for (int r = 0; r < 4; r++) {
      float d = dsum[i][r];
      d += __shfl_xor(d, 1);
      d += __shfl_xor(d, 2);
      d += __shfl_xor(d, 4);
      d += __shfl_xor(d, 8);
      dsum[i][r] = d;
    }
  if (lc == 0) {
    int mb = blockIdx.y * 2 + (w >> 1);
    for (int i = 0; i < 4; i++)
      for (int r = 0; r < 4; r++) {
        int kt = m0 + wm + 16 * i + quad * 4 + r;
        Pd[(size_t)kt * 144 + mb] = dsum[i][r];
      }
  }
}

// ---- prep: bf16 weights (Wq pre-scaled by log2e, fused QK), rel gather ----
__global__ __launch_bounds__(256) void prep_kernel(
    const float* Wq, const float* Wk, const float* Wv, const float* embd,
    const float* Wproj, const int* dist, const int* isWithin,
    __bf16* Wqkb, __bf16* Wvb, __bf16* Wpb, float* wl, __bf16* rel) {
  int tid = blockIdx.x * 256 + threadIdx.x;
  if (tid < 65536) {
    Wqkb[tid] = (__bf16)(Wq[tid] * LOG2E);  // rows 0..255: Q (exp2 domain)
    Wqkb[65536 + tid] = (__bf16)Wk[tid];    // rows 256..511: K
    Wvb[tid] = (__bf16)Wv[tid];
    int o = tid >> 8, c = tid & 255;
    Wpb[tid] = (__bf16)Wproj[o * 257 + c];
    if (c == 0) wl[o] = Wproj[o * 257 + 256];
  }
  if (tid < 16 * 256) {
    int z = tid >> 8, c = tid & 255;
    rel[tid] = (__bf16)embd[(isWithin[z] * 17 + dist[z] + 8) * 256 + c];
  }
}

// ---- transpose x [C,N] f32 -> Xt [N,C] bf16 -------------------------------
__global__ __launch_bounds__(256) void transpose_kernel(const float* x, __bf16* Xt) {
  __shared__ __bf16 tile[32][33];
  int n0 = blockIdx.x * 32;
  int c0 = blockIdx.y * 32;
  int tx = threadIdx.x & 31, ty = threadIdx.x >> 5;
  for (int i = 0; i < 32; i += 8)
    tile[ty + i][tx] = (__bf16)x[(c0 + ty + i) * NTOK + n0 + tx];
  __syncthreads();
  for (int i = 0; i < 32; i += 8)
    Xt[(n0 + ty + i) * CDIM + c0 + tx] = tile[tx][ty + i];
}

// ---- pos[16,9216] f32 = rel[16,256] x Xt[9216,256]^T ----------------------
// 144 blocks x 4 waves, one 16-token tile per wave (better CU coverage)
__global__ __launch_bounds__(256) void gemm_pos(const __bf16* rel, const __bf16* Xt,
                                                float* pos) {
  int n0 = blockIdx.x * 64 + (threadIdx.x >> 6) * 16;
  f4 acc = {};
  for (int ks = 0; ks < 256; ks += 32) {
    bf8 a = ldfrag(rel + ks, 256);
    bf8 b = ldfrag(Xt + (size_t)n0 * 256 + ks, 256);
    acc = mfma16(a, b, acc);
  }
  int l = threadIdx.x & 63, lc = l & 15, quad = l >> 4;
  for (int r = 0; r < 4; r++)
    pos[(quad * 4 + r) * NTOK + n0 + lc] = acc[r];
}

// ---- dinv_k = 1 / sum of 144 per-block partials (1 wave per kt) -----------
__global__ __launch_bounds__(256) void combine_stats(const float* __restrict__ Pd,
                                                     float* dinv) {
  int kt = blockIdx.x * 4 + (threadIdx.x >> 6);
  int lane = threadIdx.x & 63;
  const float* pd = Pd + (size_t)kt * 144;
  float d = pd[lane] + pd[lane + 64] + ((lane < 16) ? pd[lane + 128] : 0.f);
  for (int off = 1; off < 64; off <<= 1) d += __shfl_xor(d, off);
  if (lane == 0) dinv[kt] = 1.0f / d;
}

// ---- V'[c][kt] = V[c][kt] * dinv[kt], stored chunk-swizzled ---------------
// within each 32-kt group: chunk c2 (8 elems) stored at position c2^(c&3)
__global__ __launch_bounds__(256) void vscale_kernel(const __bf16* __restrict__ V,
                                                     const float* __restrict__ dinv,
                                                     __bf16* __restrict__ Vs) {
  size_t off = ((size_t)blockIdx.x * 256 + threadIdx.x) * 8;
  bf8 v = *reinterpret_cast<const bf8*>(V + off);
  int c = (int)(off / NTOK);
  int kt = (int)(off % NTOK);
  f4 dl = *reinterpret_cast<const f4*>(dinv + kt);
  f4 dh = *reinterpret_cast<const f4*>(dinv + kt + 4);
  bf8 o;
  for (int j = 0; j < 4; j++) o[j] = (__bf16)((float)v[j] * dl[j]);
  for (int j = 0; j < 4; j++) o[4 + j] = (__bf16)((float)v[4 + j] * dh[j]);
  int c2 = (kt >> 3) & 3;
  size_t dst = (size_t)c * NTOK + (kt & ~31) + (((c2 ^ (c & 3))) << 3);
  *reinterpret_cast<bf8*>(Vs + dst) = o;
}

// ---- pv: pure bf16 GEMM  Ypart[z][q][c] = P[q][kt] x V'[c][kt]^T ----------
// block 64q x 256c, 4 waves (1x4). BARRIER-FREE: wave w stages AND reads only
// Bs rows [w*64, w*64+64) (zero cross-wave sharing); per-wave ordering via
// counted vmcnt(8). A (P) loaded global->reg (content swizzle in address);
// B (V') double-buffered in LDS (32KB). 2-step issue-ahead for both streams.
template <int NSTEP>
__global__ __launch_bounds__(256, 4) void pv_kernel(const __bf16* __restrict__ P,
                                                    const __bf16* __restrict__ Vp,
                                                    float* __restrict__ Ypart) {
  __shared__ __bf16 Bs[2][256 * 32];
  const int tid = threadIdx.x;
  const int w = tid >> 6, lane = tid & 63;
  const int lc = lane & 15, quad = lane >> 4;
  const int q0 = blockIdx.x * 64;
  const int z = blockIdx.y;
  const int wn = w << 6;
  const int sb0 = z * NSTEP;
  const int swz = (quad ^ (lc & 3)) << 3;
  // per-lane A base: row q0+16i+lc of slab sb0+s, chunk quad^(row&3)
  const __bf16* gAr = P + ((size_t)sb0 * NTOK + q0 + lc) * 32 + swz;
  const size_t aStride = (size_t)NTOK * 32;
  // B staging: wave w rows [w*64, w*64+64), 4 x gl2lds of 16 rows x 32 kt
  const __bf16* gB = Vp + (size_t)(w * 64 + (lane >> 2)) * NTOK + sb0 * 32 +
                     ((lane & 3) << 3);

  bf8 afA[4], afB[4];
  // prologue: order-pinned [B(0), A(0), B(1), A(1)]
  for (int u = 0; u < 4; u++)
    gl2lds(gB + (size_t)(16 * u) * NTOK, &Bs[0][(w * 64 + 16 * u) * 32]);
  __builtin_amdgcn_sched_barrier(0);
#pragma unroll
  for (int i = 0; i < 4; i++)
    afA[i] = *reinterpret_cast<const bf8*>(gAr + i * 512);
  __builtin_amdgcn_sched_barrier(0);
  for (int u = 0; u < 4; u++)
    gl2lds(gB + (size_t)(16 * u) * NTOK + 32, &Bs[1][(w * 64 + 16 * u) * 32]);
  __builtin_amdgcn_sched_barrier(0);
#pragma unroll
  for (int i = 0; i < 4; i++)
    afB[i] = *reinterpret_cast<const bf8*>(gAr + aStride + i * 512);
  __builtin_amdgcn_sched_barrier(0);

  f4 acc[4][4] = {};

#define PV_STEP(s, CUR, AFU)                                                   \
  {                                                                            \
    asm volatile("s_waitcnt vmcnt(8)" ::: "memory");                           \
    __builtin_amdgcn_sched_barrier(0);                                         \
    bf8 bfr[4];                                                                \
    for (int j = 0; j < 4; j++)                                                \
      bfr[j] = *reinterpret_cast<const bf8*>(                                  \
          &Bs[CUR][(wn + 16 * j + lc) * 32 + swz]);                            \
    __builtin_amdgcn_s_setprio(1);                                             \
    for (int i = 0; i < 4; i++)                                                \
      for (int j = 0; j < 4; j++)                                              \
        acc[i][j] = mfma16(AFU[i], bfr[j], acc[i][j]);                         \
    __builtin_amdgcn_s_setprio(0);                                             \
    __builtin_amdgcn_sched_barrier(0);                                         \
    int sp = ((s) + 2 < NSTEP) ? (s) + 2 : NSTEP - 1;                          \
    for (int u = 0; u < 4; u++)                                                \
      gl2lds(gB + (size_t)(16 * u) * NTOK + sp * 32,                           \
             &Bs[CUR][(w * 64 + 16 * u) * 32]);                                \
    __builtin_amdgcn_sched_barrier(0);                                         \
    _Pragma("unroll") for (int i = 0; i < 4; i++) AFU[i] =                     \
        *reinterpret_cast<const bf8*>(gAr + (size_t)sp * aStride + i * 512);   \
    __builtin_amdgcn_sched_barrier(0);                                         \
  }

  for (int s = 0; s < NSTEP; s += 2) {
    PV_STEP(s, 0, afA);
    PV_STEP(s + 1, 1, afB);
  }
#undef PV_STEP

  float* Yp = Ypart + (size_t)z * NTOK * 256;
  for (int i = 0; i < 4; i++)
    for (int j = 0; j < 4; j++)
      for (int r = 0; r < 4; r++)
        Yp[(size_t)(q0 + 16 * i + quad * 4 + r) * 256 + wn + 16 * j + lc] =
            acc[i][j][r];
}

// ---- combine zp Y-partials + residual -> outT [N,C] bf16 ------------------
__global__ __launch_bounds__(256) void combine_y_kernel(const float* __restrict__ Ypart,
                                                        const __bf16* __restrict__ Xt,
                                                        __bf16* outT, int zp) {
  int i = blockIdx.x * 256 + threadIdx.x;
  f4 y = {};
  for (int z = 0; z < zp; z++) {
    f4 p = reinterpret_cast<const f4*>(Ypart + (size_t)z * NTOK * 256)[i];
    for (int t = 0; t < 4; t++) y[t] += p[t];
  }
  bfx4 xv = reinterpret_cast<const bfx4*>(Xt)[i];
  bfx4 o;
  for (int t = 0; t < 4; t++) o[t] = (__bf16)(y[t] + (float)xv[t]);
  reinterpret_cast<bfx4*>(outT)[i] = o;
}

extern "C" void kernel_launch(void* const* d_in, const int* in_sizes, int n_in,
                              void* d_out, int out_size, void* d_ws, size_t ws_size,
                              hipStream_t stream) {
  const float* x = (const float*)d_in[0];
  const float* Wq = (const float*)d_in[1];
  const float* Wk = (const float*)d_in[2];
  const float* Wv = (const float*)d_in[3];
  const float* embd = (const float*)d_in[4];
  const float* Wproj = (const float*)d_in[5];
  const int* dist = (const int*)d_in[6];
  const int* isW = (const int*)d_in[7];
  float* out = (float*)d_out;

  char* w8 = (char*)d_ws;
  __bf16* Xt = (__bf16*)(w8 + 0);            // 4,718,592
  __bf16* QKt = (__bf16*)(w8 + 4718592);     // 9,437,184 [q][512]: Q|K
  __bf16* V = (__bf16*)(w8 + 14155776);      // 4,718,592 [c][n] raw
  __bf16* Wqkb = (__bf16*)(w8 + 18874368);   // 262,144
  __bf16* Wvb = (__bf16*)(w8 + 19136512);    // 131,072
  __bf16* Wpb = (__bf16*)(w8 + 19267584);    // 131,072
  __bf16* rel = (__bf16*)(w8 + 19398656);    // 8,192
  float* wl = (float*)(w8 + 19406848);       // 1,024
  float* pos = (float*)(w8 + 19407872);      // 589,824
  float* dinv = (float*)(w8 + 20034560);     // 36,864
  __bf16* Vs = (__bf16*)(w8 + 20971520);     // 4,718,592 scaled+swizzled V'
  const size_t sOff = 29508608;
  __bf16* P = (__bf16*)(w8 + sOff);          // 169,869,312 step-tiled bf16 P
  float* Pd = (float*)(w8 + sOff + 171966464);              // 5,308,416 (+2MB pad)
  const size_t ypOff = sOff + 171966464 + 5308416;          // Ypart base
  float* Ypart = (float*)(w8 + ypOff);       // zp * 9,437,184
  __bf16* outT = (__bf16*)(w8 + sOff);       // alias P (dead after pv)

  // pick kt-split so Ypart fits (ws_size constant across calls -> graph-safe)
  static const int ZPS[] = {6, 4, 3, 2, 1};
  int zp = 1;
  for (int i = 0; i < 5; i++)
    if (ypOff + (size_t)ZPS[i] * 9437184 <= ws_size) { zp = ZPS[i]; break; }

  prep_kernel<<<256, 256, 0, stream>>>(Wq, Wk, Wv, embd, Wproj, dist, isW,
                                       Wqkb, Wvb, Wpb, wl, rel);
  transpose_kernel<<<dim3(288, 8), 256, 0, stream>>>(x, Xt);
  // QK fused: QKt[9216][512] = Xt x Wqkb^T
  gemm128<1><<<dim3(72, 4), 256, 0, stream>>>(Xt, 256, Wqkb, 256, QKt, 512, 256,
                                              nullptr, nullptr);
  // V[256][9216] = Wvb x Xt^T
  gemm128<1><<<dim3(2, 72), 256, 0, stream>>>(Wvb, 256, Xt, 256, V, NTOK, 256,
                                              nullptr, nullptr);
  gemm_pos<<<144, 256, 0, stream>>>(rel, Xt, pos);
  // P = bf16(exp2(Kt x Qt^T - 32)) step-tiled (D[kt][q]) + per-kt sum partials
  sgemm_kernel<<<dim3(72, 72), 256, 0, stream>>>(QKt + 256, QKt, P, Pd);
  combine_stats<<<2304, 256, 0, stream>>>(Pd, dinv);
  vscale_kernel<<<1152, 256, 0, stream>>>(V, dinv, Vs);
  switch (zp) {
    case 6: pv_kernel<48><<<dim3(144, 6), 256, 0, stream>>>(P, Vs, Ypart); break;
    case 4: pv_kernel<72><<<dim3(144, 4), 256, 0, stream>>>(P, Vs, Ypart); break;
    case 3: pv_kernel<96><<<dim3(144, 3), 256, 0, stream>>>(P, Vs, Ypart); break;
    case 2: pv_kernel<144><<<dim3(144, 2), 256, 0, stream>>>(P, Vs, Ypart); break;
    default: pv_kernel<288><<<dim3(144, 1), 256, 0, stream>>>(P, Vs, Ypart); break;
  }
  combine_y_kernel<<<2304, 256, 0, stream>>>(Ypart, Xt, outT, zp);
  // fused: out[z][o][n] = (Wpb x outT^T)[o][n] + wl[o]*pos[z][n]
  gemm128<4><<<dim3(2, 72, 8), 256, 0, stream>>>(Wpb, 256, outT, 256, out, NTOK, 256,
                                                 pos, wl);
}

// Round 12
// 374.745 us; speedup vs baseline: 1.0429x; 1.0429x over previous
//
#include <hip/hip_runtime.h>
#include <hip/hip_bf16.h>

typedef __bf16 bf8 __attribute__((ext_vector_type(8)));
typedef __bf16 bfx4 __attribute__((ext_vector_type(4)));
typedef float f4 __attribute__((ext_vector_type(4)));

#define NTOK 9216
#define CDIM 256
#define LOG2E 1.44269504f
#define PSHIFT 32.0f

// ---- MFMA fragment helpers (16x16x32 bf16) --------------------------------
// A[m][k]: lane m=l&15, k=(l>>4)*8+j ; Bt[n][k] same ; D: row=(l>>4)*4+reg,
// col=l&15
__device__ inline bf8 ldfrag(const __bf16* p, int ld) {
  int l = threadIdx.x & 63;
  return *reinterpret_cast<const bf8*>(p + (l & 15) * ld + ((l >> 4) << 3));
}
__device__ inline f4 mfma16(bf8 a, bf8 b, f4 c) {
  return __builtin_amdgcn_mfma_f32_16x16x32_bf16(a, b, c, 0, 0, 0);
}
// async global->LDS, 16B per lane; LDS dest = base + lane*16 (wave-uniform base)
__device__ inline void gl2lds(const __bf16* g, __bf16* l) {
  __builtin_amdgcn_global_load_lds(
      (const __attribute__((address_space(1))) void*)g,
      (__attribute__((address_space(3))) void*)l, 16, 0, 0);
}

// ---- generic GEMM: C[M][N] = A[M][K](lda) x Bt[N][K](ldb)^T ----------------
// 128x128 tile, BK=32, 4 waves in 2x2. 2-buffer counted-vmcnt pipeline.
// EPI: 4 = fused final: out[z][row][col] = acc + aux1[row]*aux0[z*NTOK+col],
//          z in [blockIdx.z*2, blockIdx.z*2+2)
template <int EPI>
__global__ __launch_bounds__(256) void gemm128(const __bf16* __restrict__ A, int lda,
                                               const __bf16* __restrict__ Bt, int ldb,
                                               void* __restrict__ Cv, int ldc, int K,
                                               const float* __restrict__ aux0,
                                               const float* __restrict__ aux1) {
  __shared__ __bf16 As[2][128 * 32];
  __shared__ __bf16 Bs[2][128 * 32];
  const int tid = threadIdx.x;
  const int w = tid >> 6, lane = tid & 63;
  const int lc = lane & 15, quad = lane >> 4;
  const int m0 = blockIdx.x * 128, n0 = blockIdx.y * 128;
  const int wm = (w & 1) << 6, wn = (w >> 1) << 6;
  const int r0 = (w * 2) * 16 + (lane >> 2);
  const int cg = (lane & 3) * 8;
  const __bf16* gA0 = A + (size_t)(m0 + r0) * lda + cg;
  const __bf16* gA1 = A + (size_t)(m0 + r0 + 16) * lda + cg;
  const __bf16* gB0 = Bt + (size_t)(n0 + r0) * ldb + cg;
  const __bf16* gB1 = Bt + (size_t)(n0 + r0 + 16) * ldb + cg;
  const int la = w * 1024;

  for (int p = 0; p < 2; p++) {
    gl2lds(gA0 + p * 32, &As[p][la]);
    gl2lds(gA1 + p * 32, &As[p][la + 512]);
    gl2lds(gB0 + p * 32, &Bs[p][la]);
    gl2lds(gB1 + p * 32, &Bs[p][la + 512]);
  }

  f4 acc[4][4] = {};
  const int nst = K / 32;
  for (int s = 0; s < nst; s++) {
    const int cur = s & 1;
    asm volatile("s_waitcnt vmcnt(4)" ::: "memory");
    __builtin_amdgcn_sched_barrier(0);
    __builtin_amdgcn_s_barrier();
    __builtin_amdgcn_sched_barrier(0);
    bf8 af[4], bfr[4];
    for (int i = 0; i < 4; i++) af[i] = ldfrag(&As[cur][(wm + 16 * i) * 32], 32);
    for (int j = 0; j < 4; j++) bfr[j] = ldfrag(&Bs[cur][(wn + 16 * j) * 32], 32);
    __builtin_amdgcn_s_setprio(1);
    for (int i = 0; i < 4; i++)
      for (int j = 0; j < 4; j++) acc[i][j] = mfma16(af[i], bfr[j], acc[i][j]);
    __builtin_amdgcn_s_setprio(0);
    __builtin_amdgcn_sched_barrier(0);
    __builtin_amdgcn_s_barrier();
    __builtin_amdgcn_sched_barrier(0);
    int sp = (s + 2 < nst) ? s + 2 : nst - 1;
    gl2lds(gA0 + sp * 32, &As[cur][la]);
    gl2lds(gA1 + sp * 32, &As[cur][la + 512]);
    gl2lds(gB0 + sp * 32, &Bs[cur][la]);
    gl2lds(gB1 + sp * 32, &Bs[cur][la + 512]);
  }
  asm volatile("s_waitcnt vmcnt(0)" ::: "memory");

  if (EPI == 4) {
    float* outp = (float*)Cv;
    const int z0 = blockIdx.z * 2;
    for (int i = 0; i < 4; i++)
      for (int r = 0; r < 4; r++) {
        int o = m0 + wm + 16 * i + quad * 4 + r;
        float wo = aux1[o];
        for (int j = 0; j < 4; j++) {
          int n = n0 + wn + 16 * j + lc;
          float b = acc[i][j][r];
          for (int z = z0; z < z0 + 2; z++)
            outp[((size_t)z * 256 + o) * NTOK + n] =
                b + wo * aux0[(size_t)z * NTOK + n];
        }
      }
  } else {
    for (int i = 0; i < 4; i++)
      for (int j = 0; j < 4; j++)
        for (int r = 0; r < 4; r++) {
          size_t idx = (size_t)(m0 + wm + 16 * i + quad * 4 + r) * ldc +
                       (n0 + wn + 16 * j + lc);
          ((__bf16*)Cv)[idx] = (__bf16)acc[i][j][r];
        }
  }
}

// ---- horizontally fused QK + V projection GEMMs (one launch, 432 blocks) ---
// bid < 288: QKt[9216][512] = Xt x Wqkb^T   (m0=(bid%72)*128, n0=(bid/72)*128)
// bid >= 288: V[256][9216] = Wvb x Xt^T     (b2=bid-288: m0=(b2%2)*128,
//                                            n0=(b2/2)*128)
__global__ __launch_bounds__(256) void qkv_kernel(const __bf16* __restrict__ Xt,
                                                  const __bf16* __restrict__ Wqkb,
                                                  __bf16* __restrict__ QKt,
                                                  const __bf16* __restrict__ Wvb,
                                                  __bf16* __restrict__ V) {
  __shared__ __bf16 As[2][128 * 32];
  __shared__ __bf16 Bs[2][128 * 32];
  const __bf16 *A, *Bt;
  __bf16* C;
  int lda, ldb, ldc, m0, n0;
  const int bid = blockIdx.x;
  if (bid < 288) {
    A = Xt; lda = 256; Bt = Wqkb; ldb = 256; C = QKt; ldc = 512;
    m0 = (bid % 72) * 128; n0 = (bid / 72) * 128;
  } else {
    int b2 = bid - 288;
    A = Wvb; lda = 256; Bt = Xt; ldb = 256; C = V; ldc = NTOK;
    m0 = (b2 % 2) * 128; n0 = (b2 / 2) * 128;
  }
  const int tid = threadIdx.x;
  const int w = tid >> 6, lane = tid & 63;
  const int lc = lane & 15, quad = lane >> 4;
  const int wm = (w & 1) << 6, wn = (w >> 1) << 6;
  const int r0 = (w * 2) * 16 + (lane >> 2);
  const int cg = (lane & 3) * 8;
  const __bf16* gA0 = A + (size_t)(m0 + r0) * lda + cg;
  const __bf16* gA1 = A + (size_t)(m0 + r0 + 16) * lda + cg;
  const __bf16* gB0 = Bt + (size_t)(n0 + r0) * ldb + cg;
  const __bf16* gB1 = Bt + (size_t)(n0 + r0 + 16) * ldb + cg;
  const int la = w * 1024;

  for (int p = 0; p < 2; p++) {
    gl2lds(gA0 + p * 32, &As[p][la]);
    gl2lds(gA1 + p * 32, &As[p][la + 512]);
    gl2lds(gB0 + p * 32, &Bs[p][la]);
    gl2lds(gB1 + p * 32, &Bs[p][la + 512]);
  }

  f4 acc[4][4] = {};
  for (int s = 0; s < 8; s++) {
    const int cur = s & 1;
    asm volatile("s_waitcnt vmcnt(4)" ::: "memory");
    __builtin_amdgcn_sched_barrier(0);
    __builtin_amdgcn_s_barrier();
    __builtin_amdgcn_sched_barrier(0);
    bf8 af[4], bfr[4];
    for (int i = 0; i < 4; i++) af[i] = ldfrag(&As[cur][(wm + 16 * i) * 32], 32);
    for (int j = 0; j < 4; j++) bfr[j] = ldfrag(&Bs[cur][(wn + 16 * j) * 32], 32);
    __builtin_amdgcn_s_setprio(1);
    for (int i = 0; i < 4; i++)
      for (int j = 0; j < 4; j++) acc[i][j] = mfma16(af[i], bfr[j], acc[i][j]);
    __builtin_amdgcn_s_setprio(0);
    __builtin_amdgcn_sched_barrier(0);
    __builtin_amdgcn_s_barrier();
    __builtin_amdgcn_sched_barrier(0);
    int sp = (s + 2 < 8) ? s + 2 : 7;
    gl2lds(gA0 + sp * 32, &As[cur][la]);
    gl2lds(gA1 + sp * 32, &As[cur][la + 512]);
    gl2lds(gB0 + sp * 32, &Bs[cur][la]);
    gl2lds(gB1 + sp * 32, &Bs[cur][la + 512]);
  }
  asm volatile("s_waitcnt vmcnt(0)" ::: "memory");

  for (int i = 0; i < 4; i++)
    for (int j = 0; j < 4; j++)
      for (int r = 0; r < 4; r++) {
        size_t idx = (size_t)(m0 + wm + 16 * i + quad * 4 + r) * ldc +
                     (n0 + wn + 16 * j + lc);
        C[idx] = (__bf16)acc[i][j][r];
      }
}

// ---- S-GEMM (swapped): D[kt][q] = Kt x Qt^T, P = bf16(exp2(D-PSHIFT)) ------
// 2-buffer double-buffered pipeline, counted vmcnt(4), 2 barriers/step.
// Epilogue: 4 consecutive kt per lane pack into one aligned b64 global store
// in the step-tiled chunk-swizzled P layout; 16-lane column-sum -> Pd.
__global__ __launch_bounds__(256) void sgemm_kernel(const __bf16* __restrict__ Kt,
                                                    const __bf16* __restrict__ Qt,
                                                    __bf16* __restrict__ Pp,
                                                    float* __restrict__ Pd) {
  __shared__ __bf16 As[2][128 * 32];
  __shared__ __bf16 Bs[2][128 * 32];
  const int tid = threadIdx.x;
  const int w = tid >> 6, lane = tid & 63;
  const int lc = lane & 15, quad = lane >> 4;
  const int m0 = blockIdx.x * 128;  // kt tile
  const int n0 = blockIdx.y * 128;  // q tile
  const int wm = (w & 1) << 6, wn = (w >> 1) << 6;
  const int r0 = w * 32 + (lane >> 2);
  const int cg = (lane & 3) * 8;
  const __bf16* gA0 = Kt + (size_t)(m0 + r0) * 512 + cg;
  const __bf16* gA1 = Kt + (size_t)(m0 + r0 + 16) * 512 + cg;
  const __bf16* gB0 = Qt + (size_t)(n0 + r0) * 512 + cg;
  const __bf16* gB1 = Qt + (size_t)(n0 + r0 + 16) * 512 + cg;
  const int la = w * 1024;

  for (int p = 0; p < 2; p++) {
    gl2lds(gA0 + p * 32, &As[p][la]);
    gl2lds(gA1 + p * 32, &As[p][la + 512]);
    gl2lds(gB0 + p * 32, &Bs[p][la]);
    gl2lds(gB1 + p * 32, &Bs[p][la + 512]);
  }

  f4 acc[4][4] = {};
  for (int s = 0; s < 8; s++) {
    const int cur = s & 1;
    asm volatile("s_waitcnt vmcnt(4)" ::: "memory");
    __builtin_amdgcn_sched_barrier(0);
    __builtin_amdgcn_s_barrier();
    __builtin_amdgcn_sched_barrier(0);
    bf8 af[4], bfr[4];
    for (int i = 0; i < 4; i++) af[i] = ldfrag(&As[cur][(wm + 16 * i) * 32], 32);
    for (int j = 0; j < 4; j++) bfr[j] = ldfrag(&Bs[cur][(wn + 16 * j) * 32], 32);
    __builtin_amdgcn_s_setprio(1);
    for (int i = 0; i < 4; i++)
      for (int j = 0; j < 4; j++) acc[i][j] = mfma16(af[i], bfr[j], acc[i][j]);
    __builtin_amdgcn_s_setprio(0);
    __builtin_amdgcn_sched_barrier(0);
    __builtin_amdgcn_s_barrier();
    __builtin_amdgcn_sched_barrier(0);
    int sp = (s + 2 < 8) ? s + 2 : 7;
    gl2lds(gA0 + sp * 32, &As[cur][la]);
    gl2lds(gA1 + sp * 32, &As[cur][la + 512]);
    gl2lds(gB0 + sp * 32, &Bs[cur][la]);
    gl2lds(gB1 + sp * 32, &Bs[cur][la + 512]);
  }

  float dsum[4][4];
  for (int i = 0; i < 4; i++)
    for (int r = 0; r < 4; r++) dsum[i][r] = 0.f;
  for (int j = 0; j < 4; j++) {
    int q = n0 + wn + 16 * j + lc;
    for (int i = 0; i < 4; i++) {
      int ktb = m0 + wm + 16 * i;
      int c2 = ((i & 1) << 1) | (quad >> 1);
      bfx4 pk;
      for (int r = 0; r < 4; r++) {
        float e = exp2f(acc[i][j][r] - PSHIFT);
        dsum[i][r] += e;
        pk[r] = (__bf16)e;
      }
      __bf16* dst = Pp + ((size_t)(ktb >> 5) * NTOK + q) * 32 +
                    ((c2 ^ (lc & 3)) << 3) + ((quad & 1) << 2);
      *reinterpret_cast<bfx4*>(dst) = pk;
    }
  }
  for (int i = 0; i < 4; i++)
    for (int r = 0; r < 4; r++) {
      float d = dsum[i][r];
      d += __shfl_xor(d, 1);
      d += __shfl_xor(d, 2);
      d += __shfl_xor(d, 4);
      d += __shfl_xor(d, 8);
      dsum[i][r] = d;
    }
  if (lc == 0) {
    int mb = blockIdx.y * 2 + (w >> 1);
    for (int i = 0; i < 4; i++)
      for (int r = 0; r < 4; r++) {
        int kt = m0 + wm + 16 * i + quad * 4 + r;
        Pd[(size_t)kt * 144 + mb] = dsum[i][r];
      }
  }
}

// ---- fused transpose + prep (one launch) ----------------------------------
// blocks [0,2304): x [C,N] f32 -> Xt [N,C] bf16 (32x32 tiles)
// blocks [2304,2560): weight prep (Wqkb/Wvb/Wpb/wl/rel)
__global__ __launch_bounds__(256) void transprep_kernel(
    const float* x, __bf16* Xt, const float* Wq, const float* Wk,
    const float* Wv, const float* embd, const float* Wproj, const int* dist,
    const int* isWithin, __bf16* Wqkb, __bf16* Wvb, __bf16* Wpb, float* wl,
    __bf16* rel) {
  if (blockIdx.x < 2304) {
    __shared__ __bf16 tile[32][33];
    int n0 = (blockIdx.x % 288) * 32;
    int c0 = (blockIdx.x / 288) * 32;
    int tx = threadIdx.x & 31, ty = threadIdx.x >> 5;
    for (int i = 0; i < 32; i += 8)
      tile[ty + i][tx] = (__bf16)x[(c0 + ty + i) * NTOK + n0 + tx];
    __syncthreads();
    for (int i = 0; i < 32; i += 8)
      Xt[(n0 + ty + i) * CDIM + c0 + tx] = tile[tx][ty + i];
  } else {
    int tid = (blockIdx.x - 2304) * 256 + threadIdx.x;
    if (tid < 65536) {
      Wqkb[tid] = (__bf16)(Wq[tid] * LOG2E);  // rows 0..255: Q (exp2 domain)
      Wqkb[65536 + tid] = (__bf16)Wk[tid];    // rows 256..511: K
      Wvb[tid] = (__bf16)Wv[tid];
      int o = tid >> 8, c = tid & 255;
      Wpb[tid] = (__bf16)Wproj[o * 257 + c];
      if (c == 0) wl[o] = Wproj[o * 257 + 256];
    }
    if (tid < 16 * 256) {
      int z = tid >> 8, c = tid & 255;
      rel[tid] = (__bf16)embd[(isWithin[z] * 17 + dist[z] + 8) * 256 + c];
    }
  }
}

// ---- pos[16,9216] f32 = rel[16,256] x Xt[9216,256]^T ----------------------
__global__ __launch_bounds__(256) void gemm_pos(const __bf16* rel, const __bf16* Xt,
                                                float* pos) {
  int n0 = blockIdx.x * 64 + (threadIdx.x >> 6) * 16;
  f4 acc = {};
  for (int ks = 0; ks < 256; ks += 32) {
    bf8 a = ldfrag(rel + ks, 256);
    bf8 b = ldfrag(Xt + (size_t)n0 * 256 + ks, 256);
    acc = mfma16(a, b, acc);
  }
  int l = threadIdx.x & 63, lc = l & 15, quad = l >> 4;
  for (int r = 0; r < 4; r++)
    pos[(quad * 4 + r) * NTOK + n0 + lc] = acc[r];
}

// ---- dinv_k = 1 / sum of 144 per-block partials (1 wave per kt) -----------
__global__ __launch_bounds__(256) void combine_stats(const float* __restrict__ Pd,
                                                     float* dinv) {
  int kt = blockIdx.x * 4 + (threadIdx.x >> 6);
  int lane = threadIdx.x & 63;
  const float* pd = Pd + (size_t)kt * 144;
  float d = pd[lane] + pd[lane + 64] + ((lane < 16) ? pd[lane + 128] : 0.f);
  for (int off = 1; off < 64; off <<= 1) d += __shfl_xor(d, off);
  if (lane == 0) dinv[kt] = 1.0f / d;
}

// ---- V'[c][kt] = V[c][kt] * dinv[kt], stored chunk-swizzled ---------------
__global__ __launch_bounds__(256) void vscale_kernel(const __bf16* __restrict__ V,
                                                     const float* __restrict__ dinv,
                                                     __bf16* __restrict__ Vs) {
  size_t off = ((size_t)blockIdx.x * 256 + threadIdx.x) * 8;
  bf8 v = *reinterpret_cast<const bf8*>(V + off);
  int c = (int)(off / NTOK);
  int kt = (int)(off % NTOK);
  f4 dl = *reinterpret_cast<const f4*>(dinv + kt);
  f4 dh = *reinterpret_cast<const f4*>(dinv + kt + 4);
  bf8 o;
  for (int j = 0; j < 4; j++) o[j] = (__bf16)((float)v[j] * dl[j]);
  for (int j = 0; j < 4; j++) o[4 + j] = (__bf16)((float)v[4 + j] * dh[j]);
  int c2 = (kt >> 3) & 3;
  size_t dst = (size_t)c * NTOK + (kt & ~31) + (((c2 ^ (c & 3))) << 3);
  *reinterpret_cast<bf8*>(Vs + dst) = o;
}

// ---- pv: pure bf16 GEMM  Ypart[z][q][c] = P[q][kt] x V'[c][kt]^T ----------
// block 64q x 256c, 4 waves (1x4). BARRIER-FREE (zero cross-wave LDS
// sharing); per-wave ordering via counted vmcnt(8). A (P) global->reg;
// B (V') double-buffered in LDS (32KB). 2-step issue-ahead both streams.
template <int NSTEP>
__global__ __launch_bounds__(256, 4) void pv_kernel(const __bf16* __restrict__ P,
                                                    const __bf16* __restrict__ Vp,
                                                    float* __restrict__ Ypart) {
  __shared__ __bf16 Bs[2][256 * 32];
  const int tid = threadIdx.x;
  const int w = tid >> 6, lane = tid & 63;
  const int lc = lane & 15, quad = lane >> 4;
  const int q0 = blockIdx.x * 64;
  const int z = blockIdx.y;
  const int wn = w << 6;
  const int sb0 = z * NSTEP;
  const int swz = (quad ^ (lc & 3)) << 3;
  const __bf16* gAr = P + ((size_t)sb0 * NTOK + q0 + lc) * 32 + swz;
  const size_t aStride = (size_t)NTOK * 32;
  const __bf16* gB = Vp + (size_t)(w * 64 + (lane >> 2)) * NTOK + sb0 * 32 +
                     ((lane & 3) << 3);

  bf8 afA[4], afB[4];
  for (int u = 0; u < 4; u++)
    gl2lds(gB + (size_t)(16 * u) * NTOK, &Bs[0][(w * 64 + 16 * u) * 32]);
  __builtin_amdgcn_sched_barrier(0);
#pragma unroll
  for (int i = 0; i < 4; i++)
    afA[i] = *reinterpret_cast<const bf8*>(gAr + i * 512);
  __builtin_amdgcn_sched_barrier(0);
  for (int u = 0; u < 4; u++)
    gl2lds(gB + (size_t)(16 * u) * NTOK + 32, &Bs[1][(w * 64 + 16 * u) * 32]);
  __builtin_amdgcn_sched_barrier(0);
#pragma unroll
  for (int i = 0; i < 4; i++)
    afB[i] = *reinterpret_cast<const bf8*>(gAr + aStride + i * 512);
  __builtin_amdgcn_sched_barrier(0);

  f4 acc[4][4] = {};

#define PV_STEP(s, CUR, AFU)                                                   \
  {                                                                            \
    asm volatile("s_waitcnt vmcnt(8)" ::: "memory");                           \
    __builtin_amdgcn_sched_barrier(0);                                         \
    bf8 bfr[4];                                                                \
    for (int j = 0; j < 4; j++)                                                \
      bfr[j] = *reinterpret_cast<const bf8*>(                                  \
          &Bs[CUR][(wn + 16 * j + lc) * 32 + swz]);                            \
    __builtin_amdgcn_s_setprio(1);                                             \
    for (int i = 0; i < 4; i++)                                                \
      for (int j = 0; j < 4; j++)                                              \
        acc[i][j] = mfma16(AFU[i], bfr[j], acc[i][j]);                         \
    __builtin_amdgcn_s_setprio(0);                                             \
    __builtin_amdgcn_sched_barrier(0);                                         \
    int sp = ((s) + 2 < NSTEP) ? (s) + 2 : NSTEP - 1;                          \
    for (int u = 0; u < 4; u++)                                                \
      gl2lds(gB + (size_t)(16 * u) * NTOK + sp * 32,                           \
             &Bs[CUR][(w * 64 + 16 * u) * 32]);                                \
    __builtin_amdgcn_sched_barrier(0);                                         \
    _Pragma("unroll") for (int i = 0; i < 4; i++) AFU[i] =                     \
        *reinterpret_cast<const bf8*>(gAr + (size_t)sp * aStride + i * 512);   \
    __builtin_amdgcn_sched_barrier(0);                                         \
  }

  for (int s = 0; s < NSTEP; s += 2) {
    PV_STEP(s, 0, afA);
    PV_STEP(s + 1, 1, afB);
  }
#undef PV_STEP

  float* Yp = Ypart + (size_t)z * NTOK * 256;
  for (int i = 0; i < 4; i++)
    for (int j = 0; j < 4; j++)
      for (int r = 0; r < 4; r++)
        Yp[(size_t)(q0 + 16 * i + quad * 4 + r) * 256 + wn + 16 * j + lc] =
            acc[i][j][r];
}

// ---- combine zp Y-partials + residual -> outT [N,C] bf16 ------------------
__global__ __launch_bounds__(256) void combine_y_kernel(const float* __restrict__ Ypart,
                                                        const __bf16* __restrict__ Xt,
                                                        __bf16* outT, int zp) {
  int i = blockIdx.x * 256 + threadIdx.x;
  f4 y = {};
  for (int z = 0; z < zp; z++) {
    f4 p = reinterpret_cast<const f4*>(Ypart + (size_t)z * NTOK * 256)[i];
    for (int t = 0; t < 4; t++) y[t] += p[t];
  }
  bfx4 xv = reinterpret_cast<const bfx4*>(Xt)[i];
  bfx4 o;
  for (int t = 0; t < 4; t++) o[t] = (__bf16)(y[t] + (float)xv[t]);
  reinterpret_cast<bfx4*>(outT)[i] = o;
}

extern "C" void kernel_launch(void* const* d_in, const int* in_sizes, int n_in,
                              void* d_out, int out_size, void* d_ws, size_t ws_size,
                              hipStream_t stream) {
  const float* x = (const float*)d_in[0];
  const float* Wq = (const float*)d_in[1];
  const float* Wk = (const float*)d_in[2];
  const float* Wv = (const float*)d_in[3];
  const float* embd = (const float*)d_in[4];
  const float* Wproj = (const float*)d_in[5];
  const int* dist = (const int*)d_in[6];
  const int* isW = (const int*)d_in[7];
  float* out = (float*)d_out;

  char* w8 = (char*)d_ws;
  __bf16* Xt = (__bf16*)(w8 + 0);            // 4,718,592
  __bf16* QKt = (__bf16*)(w8 + 4718592);     // 9,437,184 [q][512]: Q|K
  __bf16* V = (__bf16*)(w8 + 14155776);      // 4,718,592 [c][n] raw
  __bf16* Wqkb = (__bf16*)(w8 + 18874368);   // 262,144
  __bf16* Wvb = (__bf16*)(w8 + 19136512);    // 131,072
  __bf16* Wpb = (__bf16*)(w8 + 19267584);    // 131,072
  __bf16* rel = (__bf16*)(w8 + 19398656);    // 8,192
  float* wl = (float*)(w8 + 19406848);       // 1,024
  float* pos = (float*)(w8 + 19407872);      // 589,824
  float* dinv = (float*)(w8 + 20034560);     // 36,864
  __bf16* Vs = (__bf16*)(w8 + 20971520);     // 4,718,592 scaled+swizzled V'
  const size_t sOff = 29508608;
  __bf16* P = (__bf16*)(w8 + sOff);          // 169,869,312 step-tiled bf16 P
  float* Pd = (float*)(w8 + sOff + 171966464);              // 5,308,416 (+2MB pad)
  const size_t ypOff = sOff + 171966464 + 5308416;          // Ypart base
  float* Ypart = (float*)(w8 + ypOff);       // zp * 9,437,184
  __bf16* outT = (__bf16*)(w8 + sOff);       // alias P (dead after pv)

  // pick kt-split so Ypart fits (ws_size constant across calls -> graph-safe)
  static const int ZPS[] = {3, 2, 1};
  int zp = 1;
  for (int i = 0; i < 3; i++)
    if (ypOff + (size_t)ZPS[i] * 9437184 <= ws_size) { zp = ZPS[i]; break; }

  transprep_kernel<<<2560, 256, 0, stream>>>(x, Xt, Wq, Wk, Wv, embd, Wproj,
                                             dist, isW, Wqkb, Wvb, Wpb, wl, rel);
  qkv_kernel<<<432, 256, 0, stream>>>(Xt, Wqkb, QKt, Wvb, V);
  gemm_pos<<<144, 256, 0, stream>>>(rel, Xt, pos);
  // P = bf16(exp2(Kt x Qt^T - 32)) step-tiled (D[kt][q]) + per-kt sum partials
  sgemm_kernel<<<dim3(72, 72), 256, 0, stream>>>(QKt + 256, QKt, P, Pd);
  combine_stats<<<2304, 256, 0, stream>>>(Pd, dinv);
  vscale_kernel<<<1152, 256, 0, stream>>>(V, dinv, Vs);
  switch (zp) {
    case 3: pv_kernel<96><<<dim3(144, 3), 256, 0, stream>>>(P, Vs, Ypart); break;
    case 2: pv_kernel<144><<<dim3(144, 2), 256, 0, stream>>>(P, Vs, Ypart); break;
    default: pv_kernel<288><<<dim3(144, 1), 256, 0, stream>>>(P, Vs, Ypart); break;
  }
  combine_y_kernel<<<2304, 256, 0, stream>>>(Ypart, Xt, outT, zp);
  // fused: out[z][o][n] = (Wpb x outT^T)[o][n] + wl[o]*pos[z][n]
  gemm128<4><<<dim3(2, 72, 8), 256, 0, stream>>>(Wpb, 256, outT, 256, out, NTOK, 256,
                                                 pos, wl);
}